// Round 4
// baseline (460.173 us; speedup 1.0000x reference)
//
#include <hip/hip_runtime.h>
#include <hip/hip_bf16.h>
#include <math.h>

#define NN 50000
#define EE 200000
#define DD 256
#define HH 8
#define DKK 32
#define NSEG (2 * NN)
#define SCAN_BLOCKS ((NSEG + 1023) / 1024)   // 98
#define MPAD 50048                            // NN rounded up to 128-tile
#define LDQKV 1280                            // q | kt0 | kt1 | vt0 | vt1

constexpr float RSQRT_DK = 0.17677669529663687f;  // 1/sqrt(32)

__device__ __forceinline__ float bf_lo(unsigned u) { return __uint_as_float(u << 16); }
__device__ __forceinline__ float bf_hi(unsigned u) { return __uint_as_float(u & 0xffff0000u); }
__device__ __forceinline__ unsigned short f2bf(float f) {
    unsigned u = __float_as_uint(f);
    return (unsigned short)((u + 0x7fffu + ((u >> 16) & 1u)) >> 16);  // RNE
}

typedef __attribute__((ext_vector_type(8))) short bf16x8;
typedef __attribute__((ext_vector_type(4))) float f32x4;

#define GLDS16(g, l)                                                                   \
    __builtin_amdgcn_global_load_lds((const __attribute__((address_space(1))) unsigned int*)(g), \
                                     (__attribute__((address_space(3))) unsigned int*)(l), 16, 0, 0)

// ---------------------------------------------------------------------------
// Casts / weight folds
// ---------------------------------------------------------------------------
__global__ void cast_x_kernel(const float* __restrict__ x, unsigned short* __restrict__ xb) {
    const size_t i = ((size_t)blockIdx.x * 256 + threadIdx.x) * 4;  // grid covers NN*DD/4
    float4 v = *(const float4*)&x[i];
    ushort4 o;
    o.x = f2bf(v.x); o.y = f2bf(v.y); o.z = f2bf(v.z); o.w = f2bf(v.w);
    *(ushort4*)&xb[i] = o;
}

// Wt[1280][256]: col n of fused projection, transposed.
// n<256: Wq col n.  sec=(n-256)>>8: 0,1 -> Wk @ rel_att[r];  2,3 -> Wv @ rel_msg[r].
// n>=1280: Wa transpose-cast (folded cast_wa, saves a launch).
__global__ void fold_qkv_kernel(const float* __restrict__ Wq, const float* __restrict__ Wk,
                                const float* __restrict__ Wv, const float* __restrict__ bq,
                                const float* __restrict__ bk, const float* __restrict__ bv,
                                const float* __restrict__ rel_att, const float* __restrict__ rel_msg,
                                const float* __restrict__ Wa, unsigned short* __restrict__ wa_t,
                                unsigned short* __restrict__ Wt, float* __restrict__ bb) {
    const int n = blockIdx.x, kk = threadIdx.x;
    if (n >= 1280) {                       // Wa cast path
        const int nn = n - 1280;
        wa_t[(size_t)nn * 256 + kk] = f2bf(Wa[(size_t)kk * 256 + nn]);
        return;
    }
    if (n < 256) {
        Wt[(size_t)n * 256 + kk] = f2bf(Wq[(size_t)kk * 256 + n]);
        if (kk == 0) bb[n] = bq[n];
        return;
    }
    const int sec = (n - 256) >> 8;       // 0..3
    const int c = (n - 256) & 255;
    const int h = c >> 5, f = c & 31;
    const float* W    = (sec < 2) ? Wk : Wv;
    const float* bsrc = (sec < 2) ? bk : bv;
    const float* T = ((sec < 2) ? rel_att : rel_msg)
                   + (size_t)(sec & 1) * HH * DKK * DKK + (size_t)h * DKK * DKK + f;
    const float* wrow = &W[(size_t)kk * 256 + h * 32];
    float s = 0.f;
    #pragma unroll
    for (int d = 0; d < 32; ++d) s += wrow[d] * T[(size_t)d * 32];
    Wt[(size_t)n * 256 + kk] = f2bf(s);
    if (kk == 0) {
        float sb = 0.f;
        for (int d = 0; d < 32; ++d) sb += bsrc[h * 32 + d] * T[(size_t)d * 32];
        bb[n] = sb;
    }
}

// ---------------------------------------------------------------------------
// MFMA bf16 GEMM v4: C[M,N] = A[M,256] @ Bt[N,256]^T + bias.
// ONE block per 128-row M-panel; inner loop over N-tiles (QKV: 10, out: 2).
// Flattened (nt,kc) step pipeline: 80 (resp 16) steps, 3-buf staging,
// depth-2 counted vmcnt -- prologue/drain amortized 10x vs per-tile blocks.
// Per-nt epilogue goes through a DEDICATED per-wave 4KB LDS region: no
// barriers in the epilogue (avoids __syncthreads vmcnt-drain), stores stay
// in flight across the nt boundary (vmcnt(12) at the next 2 steps).
// LDS = 48KB stream + 16KB epilogue = 64KB -> 2 blocks/CU.
// Cbf: bf16 out.  Cf: fp32 out + skip-gate epilogue.
// ---------------------------------------------------------------------------
__global__ __launch_bounds__(256) void mfma_gemm(
        const unsigned short* __restrict__ A, const unsigned short* __restrict__ Bt,
        const float* __restrict__ bias,
        unsigned short* __restrict__ Cbf, float* __restrict__ Cf,
        int M, int N, int ldc, const float* __restrict__ xres, const float* __restrict__ skip) {
    __shared__ __align__(16) unsigned short As[3][8][64][8];  // 24KB (3 bufs)
    __shared__ __align__(16) unsigned short Bs[3][8][64][8];  // 24KB
    __shared__ __align__(16) unsigned short Ep[4][2048];      // 16KB, 4KB/wave
    const int t = threadIdx.x;
    const int w = t >> 6, l = t & 63;

    // ---- XCD-bijective swizzle (m204 form): hw linear id -> logical M-tile
    const int nwg = gridDim.x;
    int lin = blockIdx.x;
    {
        const int xcd = lin & 7, pos = lin >> 3;
        const int q = nwg >> 3, r = nwg & 7;
        lin = (xcd < r ? xcd * (q + 1) : r * (q + 1) + (xcd - r) * q) + pos;
    }
    const int m0 = lin * 128;
    const int wm = w & 1, wn = w >> 1;
    const int NT = N >> 7;
    const int TS = NT * 8;

    const int sr = l & 15, sq = l >> 4;
    const unsigned short* ga0 = A  + (size_t)(m0 + w * 16 + sr) * 256 + sq * 8;
    const unsigned short* ga1 = A  + (size_t)(m0 + (w + 4) * 16 + sr) * 256 + sq * 8;
    const unsigned short* gb0 = Bt + (size_t)(w * 16 + sr) * 256 + sq * 8;
    const unsigned short* gb1 = Bt + (size_t)((w + 4) * 16 + sr) * 256 + sq * 8;

#define STAGE(s_) do {                                                     \
        const int buf_ = (s_) % 3;                                         \
        const size_t aoff_ = (size_t)((s_) & 7) * 32;                      \
        const size_t boff_ = (size_t)((s_) >> 3) * (128 * 256) + aoff_;    \
        GLDS16(ga0 + aoff_, &As[buf_][w][0][0]);                           \
        GLDS16(ga1 + aoff_, &As[buf_][w + 4][0][0]);                       \
        GLDS16(gb0 + boff_, &Bs[buf_][w][0][0]);                           \
        GLDS16(gb1 + boff_, &Bs[buf_][w + 4][0][0]); } while (0)

    STAGE(0);          // 4 loads in flight
    STAGE(1);          // 8 loads in flight
    const int q4 = l >> 4, c15 = l & 15;

    for (int nt = 0; nt < NT; ++nt) {
        f32x4 acc[4][4];
        #pragma unroll
        for (int mi = 0; mi < 4; ++mi)
            #pragma unroll
            for (int ni = 0; ni < 4; ++ni) acc[mi][ni] = (f32x4){0.f, 0.f, 0.f, 0.f};

        #pragma unroll
        for (int kc = 0; kc < 8; ++kc) {
            const int s = (nt << 3) + kc;
            // wait: oldest pending stage landed. After an epilogue (nt>0,
            // kc<2) up to 8 stores are interleaved in the vm FIFO -> 12.
            if (s == TS - 1)            { asm volatile("s_waitcnt vmcnt(0)" ::: "memory"); }
            else if (nt == 0 || kc >= 2){ asm volatile("s_waitcnt vmcnt(4)" ::: "memory"); }
            else if (Cbf != nullptr)    { asm volatile("s_waitcnt vmcnt(12)" ::: "memory"); }
            else                        { asm volatile("s_waitcnt vmcnt(0)" ::: "memory"); }
            __builtin_amdgcn_s_barrier();          // all waves' stage(s) landed
            __builtin_amdgcn_sched_barrier(0);
            if (s + 2 < TS) STAGE(s + 2);          // overwrites buf read at s-1
            const int b = s % 3;
            bf16x8 af[4], bfr[4];
            #pragma unroll
            for (int i = 0; i < 4; ++i) {
                af[i]  = *(const bf16x8*)&As[b][wm * 4 + i][l][0];
                bfr[i] = *(const bf16x8*)&Bs[b][wn * 4 + i][l][0];
            }
            #pragma unroll
            for (int mi = 0; mi < 4; ++mi)
                #pragma unroll
                for (int ni = 0; ni < 4; ++ni)
                    acc[mi][ni] = __builtin_amdgcn_mfma_f32_16x16x32_bf16(af[mi], bfr[ni],
                                                                          acc[mi][ni], 0, 0, 0);
        }

        // ---- per-nt epilogue through per-wave private 4KB LDS (no barriers)
        if (Cf == nullptr) {
            unsigned short* epw = &Ep[w][0];
            #pragma unroll
            for (int hp = 0; hp < 2; ++hp) {       // 32 rows per pass
                #pragma unroll
                for (int mi2 = 0; mi2 < 2; ++mi2) {
                    const int mi = hp * 2 + mi2;
                    #pragma unroll
                    for (int ni = 0; ni < 4; ++ni) {
                        const float bcol = bias[nt * 128 + wn * 64 + ni * 16 + c15];
                        const int g = ni * 2 + (c15 >> 3);
                        #pragma unroll
                        for (int p = 0; p < 4; ++p) {
                            const int rl = mi2 * 16 + q4 * 4 + p;   // 0..31
                            epw[rl * 64 + ((g ^ (rl & 7)) << 3) + (c15 & 7)] =
                                f2bf(acc[mi][ni][p] + bcol);
                        }
                    }
                }
                asm volatile("s_waitcnt lgkmcnt(0)" ::: "memory");
                __builtin_amdgcn_sched_barrier(0);
                const int rs = l >> 3, cc = l & 7;
                #pragma unroll
                for (int i = 0; i < 4; ++i) {
                    const int rl = i * 8 + rs;                       // 0..31
                    const int row = m0 + wm * 64 + hp * 32 + rl;
                    if (row < M) {
                        uint4 v = *(const uint4*)&epw[rl * 64 + ((cc ^ (rl & 7)) << 3)];
                        *(uint4*)&Cbf[(size_t)row * (size_t)ldc + nt * 128 + wn * 64 + cc * 8] = v;
                    }
                }
            }
        } else {
            const float alpha = 1.f / (1.f + __expf(-skip[0]));
            const float beta = 1.f - alpha;
            float* epf = (float*)&Ep[w][0];        // 1024 floats
            #pragma unroll
            for (int qp = 0; qp < 4; ++qp) {       // 16 rows per pass
                #pragma unroll
                for (int ni = 0; ni < 4; ++ni) {
                    const float bcol = bias[nt * 128 + wn * 64 + ni * 16 + c15];
                    const int g = ni * 4 + (c15 >> 2);
                    #pragma unroll
                    for (int p = 0; p < 4; ++p) {
                        const int rl = q4 * 4 + p;                   // 0..15
                        epf[rl * 64 + ((g ^ (rl & 3)) << 2) + (c15 & 3)] =
                            acc[qp][ni][p] + bcol;
                    }
                }
                asm volatile("s_waitcnt lgkmcnt(0)" ::: "memory");
                __builtin_amdgcn_sched_barrier(0);
                const int cc = l & 15, rs = l >> 4;
                #pragma unroll
                for (int i = 0; i < 4; ++i) {
                    const int rl = i * 4 + rs;                       // 0..15
                    const int row = m0 + wm * 64 + qp * 16 + rl;
                    if (row < M) {
                        const int col = nt * 128 + wn * 64 + cc * 4;
                        float4 v = *(const float4*)&epf[rl * 64 + ((cc ^ (rl & 3)) << 2)];
                        float4 xr = *(const float4*)&xres[(size_t)row * 256 + col];
                        v.x = v.x * alpha + xr.x * beta;
                        v.y = v.y * alpha + xr.y * beta;
                        v.z = v.z * alpha + xr.z * beta;
                        v.w = v.w * alpha + xr.w * beta;
                        *(float4*)&Cf[(size_t)row * 256 + col] = v;
                    }
                }
            }
        }
    }
#undef STAGE
}

// ---------------------------------------------------------------------------
// CSR build: count -> 3-phase multiblock scan -> scatter. Segment = r*NN + dst.
// ---------------------------------------------------------------------------
__global__ void count_kernel(const int* __restrict__ dst, int* __restrict__ cnt) {
    int e = blockIdx.x * 256 + threadIdx.x;
    if (e < 2 * EE) atomicAdd(&cnt[(e / EE) * NN + dst[e]], 1);
}

__global__ __launch_bounds__(1024) void scan_local_kernel(const int* __restrict__ cnt,
                                                          int* __restrict__ rowptr,
                                                          int* __restrict__ bsum) {
    __shared__ int sh[1024];
    const int t = threadIdx.x;
    const int idx = blockIdx.x * 1024 + t;
    const int c = (idx < NSEG) ? cnt[idx] : 0;
    sh[t] = c;
    __syncthreads();
    #pragma unroll
    for (int ofs = 1; ofs < 1024; ofs <<= 1) {
        int v = (t >= ofs) ? sh[t - ofs] : 0;
        __syncthreads();
        sh[t] += v;
        __syncthreads();
    }
    if (idx < NSEG) rowptr[idx] = sh[t] - c;
    if (t == 1023) bsum[blockIdx.x] = sh[1023];
}

__global__ void scan_bsum_kernel(int* __restrict__ bsum, int* __restrict__ rowptr) {
    __shared__ int sh[128];
    const int t = threadIdx.x;
    const int v = (t < SCAN_BLOCKS) ? bsum[t] : 0;
    sh[t] = v;
    __syncthreads();
    #pragma unroll
    for (int ofs = 1; ofs < 128; ofs <<= 1) {
        int u = (t >= ofs) ? sh[t - ofs] : 0;
        __syncthreads();
        sh[t] += u;
        __syncthreads();
    }
    if (t < SCAN_BLOCKS) bsum[t] = sh[t] - v;
    if (t == 127) rowptr[NSEG] = sh[127];
}

// final rowptr = local + block prefix; also seed cursor (saves a D2D memcpy)
__global__ __launch_bounds__(1024) void scan_add_kernel(int* __restrict__ rowptr,
                                                        const int* __restrict__ bsum,
                                                        int* __restrict__ cursor) {
    const int idx = blockIdx.x * 1024 + threadIdx.x;
    if (idx < NSEG) {
        const int v = rowptr[idx] + bsum[blockIdx.x];
        rowptr[idx] = v;
        cursor[idx] = v;
    }
}

__global__ void scatter_kernel(const int* __restrict__ src, const int* __restrict__ dst,
                               int* __restrict__ cursor, int* __restrict__ csr_src) {
    int e = blockIdx.x * 256 + threadIdx.x;
    if (e >= 2 * EE) return;
    int seg = (e / EE) * NN + dst[e];
    int pos = atomicAdd(&cursor[seg], 1);
    csr_src[pos] = src[e];
}

// ---------------------------------------------------------------------------
// Fused attention + aggregation (one wave per (node, relation), two edges in
// flight per wave, depth-1 software pipeline, relation-combine via LDS).
// ---------------------------------------------------------------------------
__global__ __launch_bounds__(512) void node_agg_kernel(
        const unsigned short* __restrict__ qkv,
        const int* __restrict__ csr_src,
        const int* __restrict__ rowptr,
        const float* __restrict__ pri,
        unsigned short* __restrict__ tt_bf) {
    __shared__ float sh[4][256];
    const int w = threadIdx.x >> 6, lane = threadIdx.x & 63;
    const int nl = w >> 1, r = w & 1;
    const int n = blockIdx.x * 4 + nl;     // grid = NN/4 exact
    const int lh = lane & 31;              // channel lane: 8 ch each
    const int eh = lane >> 5;              // edge parity (0: even, 1: odd)
    const int h = lh >> 2;                 // head = (lh*8)/32
    const size_t coff = (size_t)lh * 8;

    // q fragment: 8 channels (both halves load the same 16B)
    const uint4 qv = *(const uint4*)&qkv[(size_t)n * LDQKV + coff];
    const float q0 = bf_lo(qv.x), q1 = bf_hi(qv.x), q2 = bf_lo(qv.y), q3 = bf_hi(qv.y);
    const float q4_ = bf_lo(qv.z), q5 = bf_hi(qv.z), q6 = bf_lo(qv.w), q7 = bf_hi(qv.w);

    const float prm = pri[r * HH + h] * RSQRT_DK;
    const int seg = r * NN + n;
    const int j0 = rowptr[seg], j1 = rowptr[seg + 1];
    const size_t kbase = 256 + (size_t)r * 256 + coff;
    const size_t vbase = 768 + (size_t)r * 256 + coff;

    float a0 = 0.f, a1 = 0.f, a2 = 0.f, a3 = 0.f, a4 = 0.f, a5 = 0.f, a6 = 0.f, a7 = 0.f;
    float den = 0.f;

    int j = j0 + eh;
    uint4 kv, vv;
    bool valid = j < j1;
    if (valid) {
        const size_t rowb = (size_t)csr_src[j] * LDQKV;
        kv = *(const uint4*)&qkv[rowb + kbase];
        vv = *(const uint4*)&qkv[rowb + vbase];
    }
    while (valid) {
        const int jn = j + 2;
        const bool validn = jn < j1;
        uint4 kvn, vvn;
        if (validn) {
            const size_t rowb = (size_t)csr_src[jn] * LDQKV;
            kvn = *(const uint4*)&qkv[rowb + kbase];   // in flight during compute
            vvn = *(const uint4*)&qkv[rowb + vbase];
        }
        float p = q0 * bf_lo(kv.x) + q1 * bf_hi(kv.x) + q2 * bf_lo(kv.y) + q3 * bf_hi(kv.y)
                + q4_ * bf_lo(kv.z) + q5 * bf_hi(kv.z) + q6 * bf_lo(kv.w) + q7 * bf_hi(kv.w);
        p += __shfl_xor(p, 1);
        p += __shfl_xor(p, 2);                 // 4-lane head group holds the dot
        const float a = __expf(p * prm);
        den += a;
        a0 += a * bf_lo(vv.x); a1 += a * bf_hi(vv.x);
        a2 += a * bf_lo(vv.y); a3 += a * bf_hi(vv.y);
        a4 += a * bf_lo(vv.z); a5 += a * bf_hi(vv.z);
        a6 += a * bf_lo(vv.w); a7 += a * bf_hi(vv.w);
        kv = kvn; vv = vvn; j = jn; valid = validn;
    }
    // combine edge-parity halves (lane ^ 32)
    den += __shfl_xor(den, 32);
    a0 += __shfl_xor(a0, 32); a1 += __shfl_xor(a1, 32);
    a2 += __shfl_xor(a2, 32); a3 += __shfl_xor(a3, 32);
    a4 += __shfl_xor(a4, 32); a5 += __shfl_xor(a5, 32);
    a6 += __shfl_xor(a6, 32); a7 += __shfl_xor(a7, 32);
    const float wgt = (den > 0.f) ? 0.5f / den : 0.f;

    // relation combine: r=0 writes LDS, r=1 adds and stores
    if (r == 0 && eh == 0) {
        sh[nl][0 * 32 + lh] = a0 * wgt; sh[nl][1 * 32 + lh] = a1 * wgt;
        sh[nl][2 * 32 + lh] = a2 * wgt; sh[nl][3 * 32 + lh] = a3 * wgt;
        sh[nl][4 * 32 + lh] = a4 * wgt; sh[nl][5 * 32 + lh] = a5 * wgt;
        sh[nl][6 * 32 + lh] = a6 * wgt; sh[nl][7 * 32 + lh] = a7 * wgt;
    }
    __syncthreads();
    if (r == 1 && eh == 0) {
        const float t0 = sh[nl][0 * 32 + lh] + a0 * wgt;
        const float t1 = sh[nl][1 * 32 + lh] + a1 * wgt;
        const float t2 = sh[nl][2 * 32 + lh] + a2 * wgt;
        const float t3 = sh[nl][3 * 32 + lh] + a3 * wgt;
        const float t4 = sh[nl][4 * 32 + lh] + a4 * wgt;
        const float t5 = sh[nl][5 * 32 + lh] + a5 * wgt;
        const float t6 = sh[nl][6 * 32 + lh] + a6 * wgt;
        const float t7 = sh[nl][7 * 32 + lh] + a7 * wgt;
        uint4 o;
        o.x = (unsigned)f2bf(t0) | ((unsigned)f2bf(t1) << 16);
        o.y = (unsigned)f2bf(t2) | ((unsigned)f2bf(t3) << 16);
        o.z = (unsigned)f2bf(t4) | ((unsigned)f2bf(t5) << 16);
        o.w = (unsigned)f2bf(t6) | ((unsigned)f2bf(t7) << 16);
        *(uint4*)&tt_bf[(size_t)n * 256 + coff] = o;
    }
}

// ---------------------------------------------------------------------------
extern "C" void kernel_launch(void* const* d_in, const int* in_sizes, int n_in,
                              void* d_out, int out_size, void* d_ws, size_t ws_size,
                              hipStream_t stream) {
    const float* x       = (const float*)d_in[0];
    const int*   src     = (const int*)d_in[1];
    const int*   dst     = (const int*)d_in[2];
    const float* Wk      = (const float*)d_in[3];
    const float* bk      = (const float*)d_in[4];
    const float* Wq      = (const float*)d_in[5];
    const float* bq      = (const float*)d_in[6];
    const float* Wv      = (const float*)d_in[7];
    const float* bv      = (const float*)d_in[8];
    const float* Wa      = (const float*)d_in[9];
    const float* ba      = (const float*)d_in[10];
    const float* rel_pri = (const float*)d_in[11];
    const float* rel_att = (const float*)d_in[12];
    const float* rel_msg = (const float*)d_in[13];
    const float* skip    = (const float*)d_in[14];
    float* out = (float*)d_out;
    char* ws = (char*)d_ws;

    const size_t ND = (size_t)NN * DD;
    size_t off = 0;
    unsigned short* x_bf   = (unsigned short*)(ws + off); off += (size_t)MPAD * DD * 2;     // 25.6MB
    unsigned short* qkv_bf = (unsigned short*)(ws + off); off += (size_t)NN * LDQKV * 2;    // 128MB
    unsigned short* tt_bf  = (unsigned short*)(ws + off); off += (size_t)MPAD * DD * 2;     // 25.6MB
    unsigned short* wqkv_t = (unsigned short*)(ws + off); off += (size_t)LDQKV * 256 * 2;
    unsigned short* wa_t   = (unsigned short*)(ws + off); off += (size_t)256 * 256 * 2;
    float*          bb     = (float*)(ws + off);          off += LDQKV * 4;
    int*            cnt    = (int*)(ws + off);            off += (size_t)NSEG * 4;
    int*            rowptr = (int*)(ws + off);            off += (size_t)(NSEG + 1) * 4;
    int*            cursor = (int*)(ws + off);            off += (size_t)NSEG * 4;
    int*            bsum   = (int*)(ws + off);            off += 128 * 4;
    int*            csr_src= (int*)(ws + off);            off += (size_t)2 * EE * 4;
    if (ws_size < off) return;

    // --- casts / folds ---
    cast_x_kernel<<<(int)(ND / 1024), 256, 0, stream>>>(x, x_bf);
    fold_qkv_kernel<<<1536, 256, 0, stream>>>(Wq, Wk, Wv, bq, bk, bv,
                                              rel_att, rel_msg, Wa, wa_t, wqkv_t, bb);

    // --- fused wide projection: qkv[50000,1280] bf16 (q | kt0 | kt1 | vt0 | vt1) ---
    mfma_gemm<<<MPAD / 128, 256, 0, stream>>>(x_bf, wqkv_t, bb, qkv_bf, nullptr,
                                              NN, LDQKV, LDQKV, nullptr, nullptr);

    // --- CSR build ---
    hipMemsetAsync(cnt, 0, (size_t)NSEG * 4, stream);
    const int eg = (2 * EE + 255) / 256;
    count_kernel<<<eg, 256, 0, stream>>>(dst, cnt);
    scan_local_kernel<<<SCAN_BLOCKS, 1024, 0, stream>>>(cnt, rowptr, bsum);
    scan_bsum_kernel<<<1, 128, 0, stream>>>(bsum, rowptr);
    scan_add_kernel<<<SCAN_BLOCKS, 1024, 0, stream>>>(rowptr, bsum, cursor);
    scatter_kernel<<<eg, 256, 0, stream>>>(src, dst, cursor, csr_src);

    // --- fused attention + gather-aggregate ---
    node_agg_kernel<<<NN / 4, 512, 0, stream>>>(qkv_bf, csr_src, rowptr,
                                                rel_pri, tt_bf);

    // --- output projection with skip gate (fp32 out) ---
    mfma_gemm<<<MPAD / 128, 256, 0, stream>>>(tt_bf, wa_t, ba, nullptr, out,
                                              NN, DD, DD, x, skip);
}

// Round 6
// 368.243 us; speedup vs baseline: 1.2496x; 1.2496x over previous
//
#include <hip/hip_runtime.h>
#include <hip/hip_bf16.h>
#include <math.h>

#define NN 50000
#define EE 200000
#define DD 256
#define HH 8
#define DKK 32
#define NSEG (2 * NN)
#define SCAN_BLOCKS ((NSEG + 1023) / 1024)   // 98
#define MPAD 50048                            // NN rounded up to 128-tile
#define LDQKV 1280                            // q | kt0 | kt1 | vt0 | vt1
#define CAST_BLOCKS 12500                     // NN*DD/4/256

constexpr float RSQRT_DK = 0.17677669529663687f;  // 1/sqrt(32)

__device__ __forceinline__ float bf_lo(unsigned u) { return __uint_as_float(u << 16); }
__device__ __forceinline__ float bf_hi(unsigned u) { return __uint_as_float(u & 0xffff0000u); }
__device__ __forceinline__ unsigned short f2bf(float f) {
    unsigned u = __float_as_uint(f);
    return (unsigned short)((u + 0x7fffu + ((u >> 16) & 1u)) >> 16);  // RNE
}

typedef __attribute__((ext_vector_type(8))) short bf16x8;
typedef __attribute__((ext_vector_type(4))) float f32x4;

#define GLDS16(g, l)                                                                   \
    __builtin_amdgcn_global_load_lds((const __attribute__((address_space(1))) unsigned int*)(g), \
                                     (__attribute__((address_space(3))) unsigned int*)(l), 16, 0, 0)

// ---------------------------------------------------------------------------
// prep: cast_x (blocks [0,12500)) + fused weight folds (blocks [12500,+1536))
// ---------------------------------------------------------------------------
__global__ void prep_kernel(const float* __restrict__ x, unsigned short* __restrict__ xb,
                            const float* __restrict__ Wq, const float* __restrict__ Wk,
                            const float* __restrict__ Wv, const float* __restrict__ bq,
                            const float* __restrict__ bk, const float* __restrict__ bv,
                            const float* __restrict__ rel_att, const float* __restrict__ rel_msg,
                            const float* __restrict__ Wa, unsigned short* __restrict__ wa_t,
                            unsigned short* __restrict__ Wt, float* __restrict__ bb) {
    if (blockIdx.x < CAST_BLOCKS) {
        const size_t i = ((size_t)blockIdx.x * 256 + threadIdx.x) * 4;
        float4 v = *(const float4*)&x[i];
        ushort4 o;
        o.x = f2bf(v.x); o.y = f2bf(v.y); o.z = f2bf(v.z); o.w = f2bf(v.w);
        *(ushort4*)&xb[i] = o;
        return;
    }
    const int n = blockIdx.x - CAST_BLOCKS, kk = threadIdx.x;
    if (n >= 1280) {                       // Wa cast path
        const int nn = n - 1280;
        wa_t[(size_t)nn * 256 + kk] = f2bf(Wa[(size_t)kk * 256 + nn]);
        return;
    }
    if (n < 256) {
        Wt[(size_t)n * 256 + kk] = f2bf(Wq[(size_t)kk * 256 + n]);
        if (kk == 0) bb[n] = bq[n];
        return;
    }
    const int sec = (n - 256) >> 8;       // 0..3
    const int c = (n - 256) & 255;
    const int h = c >> 5, f = c & 31;
    const float* W    = (sec < 2) ? Wk : Wv;
    const float* bsrc = (sec < 2) ? bk : bv;
    const float* T = ((sec < 2) ? rel_att : rel_msg)
                   + (size_t)(sec & 1) * HH * DKK * DKK + (size_t)h * DKK * DKK + f;
    const float* wrow = &W[(size_t)kk * 256 + h * 32];
    float s = 0.f;
    #pragma unroll
    for (int d = 0; d < 32; ++d) s += wrow[d] * T[(size_t)d * 32];
    Wt[(size_t)n * 256 + kk] = f2bf(s);
    if (kk == 0) {
        float sb = 0.f;
        for (int d = 0; d < 32; ++d) sb += bsrc[h * 32 + d] * T[(size_t)d * 32];
        bb[n] = sb;
    }
}

// ---------------------------------------------------------------------------
// MFMA bf16 GEMM (proven R1 version, 94us): C[M,N] = A[M,256] @ Bt[N,256]^T.
// 128x128 tile, BK=32, 256 thr (4 waves 2x2).
//  (1) XCD-bijective block swizzle (A-panel L2 locality).
//  (2) Depth-2 staging: 3 LDS buffers, STAGE(it+2) post-barrier, counted
//      s_waitcnt vmcnt(4) pre-barrier (never 0 in the loop).
//  (3) Epilogue staging XOR-swizzled -> conflict-free transpose.
// Cbf: bf16 out (ldc).  Cf: fp32 out + skip-gate epilogue (ldc=256).
// grid: (N/128, M/128).
// ---------------------------------------------------------------------------
__global__ __launch_bounds__(256) void mfma_gemm(
        const unsigned short* __restrict__ A, const unsigned short* __restrict__ Bt,
        const float* __restrict__ bias,
        unsigned short* __restrict__ Cbf, float* __restrict__ Cf,
        int M, int ldc, const float* __restrict__ xres, const float* __restrict__ skip) {
    __shared__ __align__(16) unsigned short As[3][8][64][8];  // 24KB (3 bufs)
    __shared__ __align__(16) unsigned short Bs[3][8][64][8];  // 24KB
    const int t = threadIdx.x;
    const int w = t >> 6, l = t & 63;

    // ---- XCD-bijective swizzle (m204 form): hw linear id -> logical tile id
    const int nwg = gridDim.x * gridDim.y;
    int lin = blockIdx.y * gridDim.x + blockIdx.x;
    {
        const int xcd = lin & 7, pos = lin >> 3;
        const int q = nwg >> 3, r = nwg & 7;
        lin = (xcd < r ? xcd * (q + 1) : r * (q + 1) + (xcd - r) * q) + pos;
    }
    const int n0 = (lin % gridDim.x) * 128;
    const int m0 = (lin / gridDim.x) * 128;
    const int wm = w & 1, wn = w >> 1;

    const int sr = l & 15, sq = l >> 4;
    const unsigned short* ga0 = A  + (size_t)(m0 + w * 16 + sr) * 256 + sq * 8;
    const unsigned short* ga1 = A  + (size_t)(m0 + (w + 4) * 16 + sr) * 256 + sq * 8;
    const unsigned short* gb0 = Bt + (size_t)(n0 + w * 16 + sr) * 256 + sq * 8;
    const unsigned short* gb1 = Bt + (size_t)(n0 + (w + 4) * 16 + sr) * 256 + sq * 8;

#define STAGE(buf, k0) do {                    \
        GLDS16(ga0 + (k0), &As[buf][w][0][0]); \
        GLDS16(ga1 + (k0), &As[buf][w + 4][0][0]); \
        GLDS16(gb0 + (k0), &Bs[buf][w][0][0]); \
        GLDS16(gb1 + (k0), &Bs[buf][w + 4][0][0]); } while (0)

    f32x4 acc[4][4];
    #pragma unroll
    for (int mi = 0; mi < 4; ++mi)
        #pragma unroll
        for (int ni = 0; ni < 4; ++ni) acc[mi][ni] = (f32x4){0.f, 0.f, 0.f, 0.f};

    STAGE(0, 0);       // 4 loads in flight
    STAGE(1, 32);      // 8 loads in flight
    #pragma unroll
    for (int it = 0; it < 8; ++it) {
        // wait until the oldest stage (buf it%3) has landed; keep the rest in flight
        if (it < 7) { asm volatile("s_waitcnt vmcnt(4)" ::: "memory"); }
        else        { asm volatile("s_waitcnt vmcnt(0)" ::: "memory"); }
        __builtin_amdgcn_s_barrier();          // all waves' stage(it) landed;
        __builtin_amdgcn_sched_barrier(0);     // and iter it-1 reads complete
        if (it < 6) {
            STAGE((it + 2) % 3, (it + 2) * 32);  // overwrites buf read at it-1: safe post-barrier
        }
        const int b = it % 3;
        bf16x8 af[4], bfr[4];
        #pragma unroll
        for (int i = 0; i < 4; ++i) {
            af[i]  = *(const bf16x8*)&As[b][wm * 4 + i][l][0];
            bfr[i] = *(const bf16x8*)&Bs[b][wn * 4 + i][l][0];
        }
        #pragma unroll
        for (int mi = 0; mi < 4; ++mi)
            #pragma unroll
            for (int ni = 0; ni < 4; ++ni)
                acc[mi][ni] = __builtin_amdgcn_mfma_f32_16x16x32_bf16(af[mi], bfr[ni],
                                                                      acc[mi][ni], 0, 0, 0);
    }
    __syncthreads();  // all LDS reads done; staging LDS now reused by epilogue

    // per-wave 8KB LDS region for transpose (waves 0,1 in As; 2,3 in Bs)
    unsigned short* ep = (w < 2) ? &As[0][0][0][0] : &Bs[0][0][0][0];
    ep += (w & 1) * 4096;
    const int q4 = l >> 4, c15 = l & 15;

    if (Cf == nullptr) {
        // ---- bf16 path: stage 64x64 ushort (16B-group XOR-swizzled by row&7),
        //      store uint4 (8 rows x 128B per instr)
        #pragma unroll
        for (int ni = 0; ni < 4; ++ni) {
            const float bcol = bias[n0 + wn * 64 + ni * 16 + c15];
            const int g = ni * 2 + (c15 >> 3);
            #pragma unroll
            for (int mi = 0; mi < 4; ++mi)
                #pragma unroll
                for (int p = 0; p < 4; ++p) {
                    const int row = mi * 16 + q4 * 4 + p;
                    ep[row * 64 + ((g ^ (row & 7)) << 3) + (c15 & 7)] =
                        f2bf(acc[mi][ni][p] + bcol);
                }
        }
        __syncthreads();
        const int rs = l >> 3, cc = l & 7;
        #pragma unroll
        for (int i = 0; i < 8; ++i) {
            const int rl = i * 8 + rs;
            const int row = m0 + wm * 64 + rl;
            if (row < M) {
                uint4 v = *(const uint4*)&ep[rl * 64 + ((cc ^ (rl & 7)) << 3)];
                *(uint4*)&Cbf[(size_t)row * (size_t)ldc + n0 + wn * 64 + cc * 8] = v;
            }
        }
    } else {
        // ---- fp32 + skip path: two passes of 32 rows, float4 stores
        const float alpha = 1.f / (1.f + __expf(-skip[0]));
        const float beta = 1.f - alpha;
        float* epf = (float*)ep;   // 2048 floats = 32 x 64
        #pragma unroll
        for (int half = 0; half < 2; ++half) {
            __syncthreads();
            #pragma unroll
            for (int mi2 = 0; mi2 < 2; ++mi2) {
                const int mi = half * 2 + mi2;
                #pragma unroll
                for (int ni = 0; ni < 4; ++ni) {
                    const float bcol = bias[n0 + wn * 64 + ni * 16 + c15];
                    const int g = ni * 4 + (c15 >> 2);
                    #pragma unroll
                    for (int p = 0; p < 4; ++p) {
                        const int row = mi2 * 16 + q4 * 4 + p;
                        epf[row * 64 + ((g ^ (row & 7)) << 2) + (c15 & 3)] =
                            acc[mi][ni][p] + bcol;
                    }
                }
            }
            __syncthreads();
            const int cc = l & 15, rs = l >> 4;
            #pragma unroll
            for (int i = 0; i < 8; ++i) {
                const int rl = i * 4 + rs;
                const int row = m0 + wm * 64 + half * 32 + rl;
                if (row < M) {
                    const int col = n0 + wn * 64 + cc * 4;
                    float4 v = *(const float4*)&epf[rl * 64 + ((cc ^ (rl & 7)) << 2)];
                    float4 xr = *(const float4*)&xres[(size_t)row * 256 + col];
                    v.x = v.x * alpha + xr.x * beta;
                    v.y = v.y * alpha + xr.y * beta;
                    v.z = v.z * alpha + xr.z * beta;
                    v.w = v.w * alpha + xr.w * beta;
                    *(float4*)&Cf[(size_t)row * 256 + col] = v;
                }
            }
        }
    }
#undef STAGE
}

// ---------------------------------------------------------------------------
// CSR build: memset -> count -> local scan -> (bsum-scan fused) add -> scatter.
// Segment = r*NN + dst.
// ---------------------------------------------------------------------------
__global__ void count_kernel(const int* __restrict__ dst, int* __restrict__ cnt) {
    int e = blockIdx.x * 256 + threadIdx.x;
    if (e < 2 * EE) atomicAdd(&cnt[(e / EE) * NN + dst[e]], 1);
}

__global__ __launch_bounds__(1024) void scan_local_kernel(const int* __restrict__ cnt,
                                                          int* __restrict__ rowptr,
                                                          int* __restrict__ bsum) {
    __shared__ int sh[1024];
    const int t = threadIdx.x;
    const int idx = blockIdx.x * 1024 + t;
    const int c = (idx < NSEG) ? cnt[idx] : 0;
    sh[t] = c;
    __syncthreads();
    #pragma unroll
    for (int ofs = 1; ofs < 1024; ofs <<= 1) {
        int v = (t >= ofs) ? sh[t - ofs] : 0;
        __syncthreads();
        sh[t] += v;
        __syncthreads();
    }
    if (idx < NSEG) rowptr[idx] = sh[t] - c;
    if (t == 1023) bsum[blockIdx.x] = sh[1023];
}

// fused: every block scans the 98 block-sums in LDS (cheap, redundant),
// adds its own exclusive prefix, seeds cursor; block 0 writes the total.
// Replaces scan_bsum + scan_add (one launch fewer); bsum left unmodified.
__global__ __launch_bounds__(1024) void scan_add_kernel(int* __restrict__ rowptr,
                                                        const int* __restrict__ bsum,
                                                        int* __restrict__ cursor) {
    __shared__ int sb[128];
    const int t = threadIdx.x;
    if (t < 128) sb[t] = (t < SCAN_BLOCKS) ? bsum[t] : 0;
    __syncthreads();
    #pragma unroll
    for (int ofs = 1; ofs < 128; ofs <<= 1) {
        int u = 0;
        if (t < 128 && t >= ofs) u = sb[t - ofs];
        __syncthreads();
        if (t < 128) sb[t] += u;
        __syncthreads();
    }
    // sb = inclusive scan of block sums
    const int pre = sb[blockIdx.x] - bsum[blockIdx.x];   // exclusive prefix
    const int idx = blockIdx.x * 1024 + t;
    if (idx < NSEG) {
        const int v = rowptr[idx] + pre;
        rowptr[idx] = v;
        cursor[idx] = v;
    }
    if (blockIdx.x == 0 && t == 127) rowptr[NSEG] = sb[127];
}

__global__ void scatter_kernel(const int* __restrict__ src, const int* __restrict__ dst,
                               int* __restrict__ cursor, int* __restrict__ csr_src) {
    int e = blockIdx.x * 256 + threadIdx.x;
    if (e >= 2 * EE) return;
    int seg = (e / EE) * NN + dst[e];
    int pos = atomicAdd(&cursor[seg], 1);
    csr_src[pos] = src[e];
}

// ---------------------------------------------------------------------------
// Fused attention + aggregation (one wave per (node, relation), two edges in
// flight per wave, depth-1 software pipeline, relation-combine via LDS).
// ---------------------------------------------------------------------------
__global__ __launch_bounds__(512) void node_agg_kernel(
        const unsigned short* __restrict__ qkv,
        const int* __restrict__ csr_src,
        const int* __restrict__ rowptr,
        const float* __restrict__ pri,
        unsigned short* __restrict__ tt_bf) {
    __shared__ float sh[4][256];
    const int w = threadIdx.x >> 6, lane = threadIdx.x & 63;
    const int nl = w >> 1, r = w & 1;
    const int n = blockIdx.x * 4 + nl;     // grid = NN/4 exact
    const int lh = lane & 31;              // channel lane: 8 ch each
    const int eh = lane >> 5;              // edge parity (0: even, 1: odd)
    const int h = lh >> 2;                 // head = (lh*8)/32
    const size_t coff = (size_t)lh * 8;

    // q fragment: 8 channels (both halves load the same 16B)
    const uint4 qv = *(const uint4*)&qkv[(size_t)n * LDQKV + coff];
    const float q0 = bf_lo(qv.x), q1 = bf_hi(qv.x), q2 = bf_lo(qv.y), q3 = bf_hi(qv.y);
    const float q4_ = bf_lo(qv.z), q5 = bf_hi(qv.z), q6 = bf_lo(qv.w), q7 = bf_hi(qv.w);

    const float prm = pri[r * HH + h] * RSQRT_DK;
    const int seg = r * NN + n;
    const int j0 = rowptr[seg], j1 = rowptr[seg + 1];
    const size_t kbase = 256 + (size_t)r * 256 + coff;
    const size_t vbase = 768 + (size_t)r * 256 + coff;

    float a0 = 0.f, a1 = 0.f, a2 = 0.f, a3 = 0.f, a4 = 0.f, a5 = 0.f, a6 = 0.f, a7 = 0.f;
    float den = 0.f;

    int j = j0 + eh;
    uint4 kv, vv;
    bool valid = j < j1;
    if (valid) {
        const size_t rowb = (size_t)csr_src[j] * LDQKV;
        kv = *(const uint4*)&qkv[rowb + kbase];
        vv = *(const uint4*)&qkv[rowb + vbase];
    }
    while (valid) {
        const int jn = j + 2;
        const bool validn = jn < j1;
        uint4 kvn, vvn;
        if (validn) {
            const size_t rowb = (size_t)csr_src[jn] * LDQKV;
            kvn = *(const uint4*)&qkv[rowb + kbase];   // in flight during compute
            vvn = *(const uint4*)&qkv[rowb + vbase];
        }
        float p = q0 * bf_lo(kv.x) + q1 * bf_hi(kv.x) + q2 * bf_lo(kv.y) + q3 * bf_hi(kv.y)
                + q4_ * bf_lo(kv.z) + q5 * bf_hi(kv.z) + q6 * bf_lo(kv.w) + q7 * bf_hi(kv.w);
        p += __shfl_xor(p, 1);
        p += __shfl_xor(p, 2);                 // 4-lane head group holds the dot
        const float a = __expf(p * prm);
        den += a;
        a0 += a * bf_lo(vv.x); a1 += a * bf_hi(vv.x);
        a2 += a * bf_lo(vv.y); a3 += a * bf_hi(vv.y);
        a4 += a * bf_lo(vv.z); a5 += a * bf_hi(vv.z);
        a6 += a * bf_lo(vv.w); a7 += a * bf_hi(vv.w);
        kv = kvn; vv = vvn; j = jn; valid = validn;
    }
    // combine edge-parity halves (lane ^ 32)
    den += __shfl_xor(den, 32);
    a0 += __shfl_xor(a0, 32); a1 += __shfl_xor(a1, 32);
    a2 += __shfl_xor(a2, 32); a3 += __shfl_xor(a3, 32);
    a4 += __shfl_xor(a4, 32); a5 += __shfl_xor(a5, 32);
    a6 += __shfl_xor(a6, 32); a7 += __shfl_xor(a7, 32);
    const float wgt = (den > 0.f) ? 0.5f / den : 0.f;

    // relation combine: r=0 writes LDS, r=1 adds and stores
    if (r == 0 && eh == 0) {
        sh[nl][0 * 32 + lh] = a0 * wgt; sh[nl][1 * 32 + lh] = a1 * wgt;
        sh[nl][2 * 32 + lh] = a2 * wgt; sh[nl][3 * 32 + lh] = a3 * wgt;
        sh[nl][4 * 32 + lh] = a4 * wgt; sh[nl][5 * 32 + lh] = a5 * wgt;
        sh[nl][6 * 32 + lh] = a6 * wgt; sh[nl][7 * 32 + lh] = a7 * wgt;
    }
    __syncthreads();
    if (r == 1 && eh == 0) {
        const float t0 = sh[nl][0 * 32 + lh] + a0 * wgt;
        const float t1 = sh[nl][1 * 32 + lh] + a1 * wgt;
        const float t2 = sh[nl][2 * 32 + lh] + a2 * wgt;
        const float t3 = sh[nl][3 * 32 + lh] + a3 * wgt;
        const float t4 = sh[nl][4 * 32 + lh] + a4 * wgt;
        const float t5 = sh[nl][5 * 32 + lh] + a5 * wgt;
        const float t6 = sh[nl][6 * 32 + lh] + a6 * wgt;
        const float t7 = sh[nl][7 * 32 + lh] + a7 * wgt;
        uint4 o;
        o.x = (unsigned)f2bf(t0) | ((unsigned)f2bf(t1) << 16);
        o.y = (unsigned)f2bf(t2) | ((unsigned)f2bf(t3) << 16);
        o.z = (unsigned)f2bf(t4) | ((unsigned)f2bf(t5) << 16);
        o.w = (unsigned)f2bf(t6) | ((unsigned)f2bf(t7) << 16);
        *(uint4*)&tt_bf[(size_t)n * 256 + coff] = o;
    }
}

// ---------------------------------------------------------------------------
extern "C" void kernel_launch(void* const* d_in, const int* in_sizes, int n_in,
                              void* d_out, int out_size, void* d_ws, size_t ws_size,
                              hipStream_t stream) {
    const float* x       = (const float*)d_in[0];
    const int*   src     = (const int*)d_in[1];
    const int*   dst     = (const int*)d_in[2];
    const float* Wk      = (const float*)d_in[3];
    const float* bk      = (const float*)d_in[4];
    const float* Wq      = (const float*)d_in[5];
    const float* bq      = (const float*)d_in[6];
    const float* Wv      = (const float*)d_in[7];
    const float* bv      = (const float*)d_in[8];
    const float* Wa      = (const float*)d_in[9];
    const float* ba      = (const float*)d_in[10];
    const float* rel_pri = (const float*)d_in[11];
    const float* rel_att = (const float*)d_in[12];
    const float* rel_msg = (const float*)d_in[13];
    const float* skip    = (const float*)d_in[14];
    float* out = (float*)d_out;
    char* ws = (char*)d_ws;

    size_t off = 0;
    unsigned short* x_bf   = (unsigned short*)(ws + off); off += (size_t)MPAD * DD * 2;     // 25.6MB
    unsigned short* qkv_bf = (unsigned short*)(ws + off); off += (size_t)NN * LDQKV * 2;    // 128MB
    unsigned short* tt_bf  = (unsigned short*)(ws + off); off += (size_t)MPAD * DD * 2;     // 25.6MB
    unsigned short* wqkv_t = (unsigned short*)(ws + off); off += (size_t)LDQKV * 256 * 2;
    unsigned short* wa_t   = (unsigned short*)(ws + off); off += (size_t)256 * 256 * 2;
    float*          bb     = (float*)(ws + off);          off += LDQKV * 4;
    int*            cnt    = (int*)(ws + off);            off += (size_t)NSEG * 4;
    int*            rowptr = (int*)(ws + off);            off += (size_t)(NSEG + 1) * 4;
    int*            cursor = (int*)(ws + off);            off += (size_t)NSEG * 4;
    int*            bsum   = (int*)(ws + off);            off += 128 * 4;
    int*            csr_src= (int*)(ws + off);            off += (size_t)2 * EE * 4;
    if (ws_size < off) return;

    // --- prep: cast x + fold weights (one launch) ---
    prep_kernel<<<CAST_BLOCKS + 1536, 256, 0, stream>>>(
        x, x_bf, Wq, Wk, Wv, bq, bk, bv, rel_att, rel_msg, Wa, wa_t, wqkv_t, bb);

    // --- fused wide projection: qkv[50000,1280] bf16 (q | kt0 | kt1 | vt0 | vt1) ---
    dim3 g_qkv(LDQKV / 128, MPAD / 128);   // N-tiles fastest -> A-panel reuse
    mfma_gemm<<<g_qkv, 256, 0, stream>>>(x_bf, wqkv_t, bb, qkv_bf, nullptr,
                                         NN, LDQKV, nullptr, nullptr);

    // --- CSR build (5 dispatches) ---
    hipMemsetAsync(cnt, 0, (size_t)NSEG * 4, stream);
    const int eg = (2 * EE + 255) / 256;
    count_kernel<<<eg, 256, 0, stream>>>(dst, cnt);
    scan_local_kernel<<<SCAN_BLOCKS, 1024, 0, stream>>>(cnt, rowptr, bsum);
    scan_add_kernel<<<SCAN_BLOCKS, 1024, 0, stream>>>(rowptr, bsum, cursor);
    scatter_kernel<<<eg, 256, 0, stream>>>(src, dst, cursor, csr_src);

    // --- fused attention + gather-aggregate ---
    node_agg_kernel<<<NN / 4, 512, 0, stream>>>(qkv_bf, csr_src, rowptr,
                                                rel_pri, tt_bf);

    // --- output projection with skip gate (fp32 out) ---
    dim3 g_out(DD / 128, MPAD / 128);
    mfma_gemm<<<g_out, 256, 0, stream>>>(tt_bf, wa_t, ba, nullptr, out,
                                         NN, DD, x, skip);
}